// Round 5
// baseline (275.601 us; speedup 1.0000x reference)
//
#include <hip/hip_runtime.h>
#include <cstdint>
#include <cstddef>

// Problem constants: B=4, S=2048, D=1024, H=4096, M = B*S = 8192.
#define MROWS 8192
#define DDIM  1024
#define HDIM  4096

typedef __bf16 bf16x8 __attribute__((ext_vector_type(8)));
typedef float  f32x4  __attribute__((ext_vector_type(4)));

typedef __attribute__((address_space(1))) void* as1_vp;
typedef __attribute__((address_space(3))) void* as3_vp;

__device__ __forceinline__ unsigned short f2bf(float f) {
  unsigned int u = __builtin_bit_cast(unsigned int, f);
  u += 0x7fffu + ((u >> 16) & 1u);   // RNE
  return (unsigned short)(u >> 16);
}
__device__ __forceinline__ float bf2f(unsigned short h) {
  return __builtin_bit_cast(float, (unsigned int)h << 16);
}

// fast gelu: tanh-form, exp2+rcp based. |err vs exact erf-gelu| < ~1e-3.
__device__ __forceinline__ float fast_gelu(float x) {
  float x3 = x * x * x;
  float z = 0.7978845608028654f * x + 0.03567740814f * x3;
  float e = __builtin_amdgcn_exp2f(z * 2.8853900817779268f); // exp(2z)
  float t = 1.0f - 2.0f * __builtin_amdgcn_rcpf(e + 1.0f);   // tanh(z)
  return 0.5f * x * (1.0f + t);
}

__device__ __forceinline__ void gld_lds16(const unsigned short* g, unsigned short* lds) {
  __builtin_amdgcn_global_load_lds((as1_vp)(uintptr_t)g, (as3_vp)lds, 16, 0, 0);
}

#define VMW(n)  asm volatile("s_waitcnt vmcnt(" #n ")" ::: "memory")
#define LKWN(n) asm volatile("s_waitcnt lgkmcnt(" #n ")" ::: "memory")
#define BAR()   asm volatile("s_barrier" ::: "memory")
#define SB0()   __builtin_amdgcn_sched_barrier(0)

// pre_kernel: blocks [0,8192) convert W1,W2 fp32->bf16 (float4 granule);
// blocks [8192,10240) do p1 (wave per row) and emit xb.
__global__ __launch_bounds__(256) void pre_kernel(
    const float* __restrict__ x, const float* __restrict__ w1,
    const float* __restrict__ w2, unsigned short* __restrict__ xb,
    unsigned short* __restrict__ w1b, unsigned short* __restrict__ w2b,
    float* __restrict__ p1) {
  if (blockIdx.x < 8192) {
    int i = blockIdx.x * 256 + threadIdx.x;     // 0..2097151
    const float* src; unsigned short* dst; int off;
    if (i < 1048576) { src = w1; dst = w1b; off = i; }
    else             { src = w2; dst = w2b; off = i - 1048576; }
    float4 v = ((const float4*)src)[off];
    ushort4 o;
    o.x = f2bf(v.x); o.y = f2bf(v.y); o.z = f2bf(v.z); o.w = f2bf(v.w);
    ((ushort4*)dst)[off] = o;
    return;
  }
  const int bid = blockIdx.x - 8192;
  const int wave = threadIdx.x >> 6, lane = threadIdx.x & 63;
  const int m = bid * 4 + wave;
  const int b = m >> 11;
  const float4* xrow4 = (const float4*)(x + (size_t)m * DDIM);
  const float4* od4   = (const float4*)(x + ((size_t)b * 2048 + 2) * DDIM);
  ushort4* xbrow4 = (ushort4*)(xb + (size_t)m * DDIM);
  float a0 = 0.f, a1 = 0.f, a2 = 0.f, a3 = 0.f;
#pragma unroll
  for (int it = 0; it < 4; ++it) {
    int g = it * 64 + lane;
    float4 v = xrow4[g];
    ushort4 o; o.x = f2bf(v.x); o.y = f2bf(v.y); o.z = f2bf(v.z); o.w = f2bf(v.w);
    xbrow4[g] = o;
    float4 o0 = od4[g];
    float4 o1 = od4[512 + g];
    float4 o2 = od4[1024 + g];
    float4 o3 = od4[1536 + g];
    a0 += v.x * o0.x + v.y * o0.y + v.z * o0.z + v.w * o0.w;
    a1 += v.x * o1.x + v.y * o1.y + v.z * o1.z + v.w * o1.w;
    a2 += v.x * o2.x + v.y * o2.y + v.z * o2.z + v.w * o2.w;
    a3 += v.x * o3.x + v.y * o3.y + v.z * o3.z + v.w * o3.w;
  }
#pragma unroll
  for (int off = 32; off > 0; off >>= 1) {
    a0 += __shfl_down(a0, off);
    a1 += __shfl_down(a1, off);
    a2 += __shfl_down(a2, off);
    a3 += __shfl_down(a3, off);
  }
  if (lane == 0) {
    float4 r; r.x = a0; r.y = a1; r.z = a2; r.w = a3;
    ((float4*)p1)[m] = r;
  }
}

// ---------------------------------------------------------------------------
// GEMM1 v4: 256x256, BK=32, ring-3 (96 KB), frag double-buffer (sets A/B)
// with COUNTED lgkmcnt. Per tile t:
//   STAGE(t+2); VMW(4); BAR1;                       // t+1 published
//   rd_ph1(a47 of t)           [4 ds_reads]
//   LKWN(4)  -> ph0(t)'s 8 reads (issued body t-1) retired; a47 in flight
//   MFMA_ph0(t) [16]           // a47 reads grind underneath
//   rd_ph0(t+1 -> other set)   [8 ds_reads]
//   LKWN(8)  -> a47(t) retired; ph0(t+1) in flight under MFMA_ph1
//   BAR2; MFMA_ph1(t) [16]
// WAR proof: STAGE(t+2) overwrites buf(t-1); its last reads (a47(t-1))
// retired at body t-1's LKWN(8) which precedes body t-1's BAR2. Reads of
// buf t+1 issue only after this body's VMW(4)+BAR1. lgkmcnt ledger per
// wait is exact (DS queue retires in order; gld_lds counts vmcnt only —
// if it also counted lgkm the waits only over-wait, still safe).
// ---------------------------------------------------------------------------
__global__ __launch_bounds__(512, 2) void gemm1_kernel(
    const unsigned short* __restrict__ xb, const unsigned short* __restrict__ w1b,
    const float* __restrict__ x, const float* __restrict__ b1,
    const float* __restrict__ p1, const float* __restrict__ scale_p,
    unsigned short* __restrict__ hact) {
  __shared__ __align__(16) unsigned short As[3 * 256 * 32];   // 48 KB
  __shared__ __align__(16) unsigned short Bs[3 * 256 * 32];   // 48 KB

  const int id = blockIdx.x;                 // 512 blocks
  const int xcd = id & 7, w = id >> 3;       // XCD-contiguous m-bands
  const int m0 = (xcd * 4 + (w & 3)) * 256;  // 32 m-tiles
  const int n0 = (w >> 2) * 256;             // 16 n-tiles

  const int tid  = threadIdx.x;
  const int wave = tid >> 6, lane = tid & 63;
  const int quad = lane >> 4, l16 = lane & 15;
  const int wm2  = wave >> 2;                // 0..1 -> 128-row half
  const int wn2  = wave & 3;                 // 0..3 -> 64-col slice

  const unsigned short *gA0, *gA1, *gB0, *gB1;
  {
    int idx = tid;
    int r = idx >> 2, sl = idx & 3, c = (sl - (r >> 1)) & 3;
    gA0 = xb  + (size_t)(m0 + r) * DDIM + c * 8;
    gB0 = w1b + (size_t)(n0 + r) * DDIM + c * 8;
    idx = 512 + tid;
    r = idx >> 2; sl = idx & 3; c = (sl - (r >> 1)) & 3;
    gA1 = xb  + (size_t)(m0 + r) * DDIM + c * 8;
    gB1 = w1b + (size_t)(n0 + r) * DDIM + c * 8;
  }
  const int ldsOff0 = (wave * 64) * 8;         // wave-uniform halfword offsets
  const int ldsOff1 = (512 + wave * 64) * 8;

#define STAGE1(tt, sb) do {                                   \
    const int _k = (tt) * 32;                                 \
    unsigned short* _a = &As[(sb) * 8192];                    \
    unsigned short* _b = &Bs[(sb) * 8192];                    \
    gld_lds16(gA0 + _k, _a + ldsOff0);                        \
    gld_lds16(gA1 + _k, _a + ldsOff1);                        \
    gld_lds16(gB0 + _k, _b + ldsOff0);                        \
    gld_lds16(gB1 + _k, _b + ldsOff1);                        \
  } while (0)

  f32x4 acc[8][4];
  const f32x4 z = {0.f, 0.f, 0.f, 0.f};
#pragma unroll
  for (int i = 0; i < 8; ++i)
#pragma unroll
    for (int j = 0; j < 4; ++j) acc[i][j] = z;

  // two frag sets (ping-pong), all indexing static after unroll
  bf16x8 a03A[4], a47A[4], bA[4];
  bf16x8 a03B[4], a47B[4], bB[4];

  auto rd_ph0 = [&](const unsigned short* Ab, const unsigned short* Bb,
                    bf16x8 (&aa)[4], bf16x8 (&bb)[4]) {
#pragma unroll
    for (int j = 0; j < 4; ++j) {
      const int rb = wn2 * 64 + j * 16 + l16;
      bb[j] = *(const bf16x8*)(Bb + rb * 32 + ((quad + (rb >> 1)) & 3) * 8);
    }
#pragma unroll
    for (int i = 0; i < 4; ++i) {
      const int ra = wm2 * 128 + i * 16 + l16;
      aa[i] = *(const bf16x8*)(Ab + ra * 32 + ((quad + (ra >> 1)) & 3) * 8);
    }
  };
  auto rd_ph1 = [&](const unsigned short* Ab, bf16x8 (&aa)[4]) {
#pragma unroll
    for (int i = 0; i < 4; ++i) {
      const int ra = wm2 * 128 + (i + 4) * 16 + l16;
      aa[i] = *(const bf16x8*)(Ab + ra * 32 + ((quad + (ra >> 1)) & 3) * 8);
    }
  };
  auto mf_ph0 = [&](bf16x8 (&aa)[4], bf16x8 (&bb)[4]) {
    __builtin_amdgcn_s_setprio(1);
#pragma unroll
    for (int i = 0; i < 4; ++i)
#pragma unroll
      for (int j = 0; j < 4; ++j)
        acc[i][j] = __builtin_amdgcn_mfma_f32_16x16x32_bf16(aa[i], bb[j], acc[i][j], 0, 0, 0);
    __builtin_amdgcn_s_setprio(0);
  };
  auto mf_ph1 = [&](bf16x8 (&aa)[4], bf16x8 (&bb)[4]) {
    __builtin_amdgcn_s_setprio(1);
#pragma unroll
    for (int i = 0; i < 4; ++i)
#pragma unroll
      for (int j = 0; j < 4; ++j)
        acc[4 + i][j] = __builtin_amdgcn_mfma_f32_16x16x32_bf16(aa[i], bb[j], acc[4 + i][j], 0, 0, 0);
    __builtin_amdgcn_s_setprio(0);
  };

#define G1BODY(tt, CB, NB, SB, CUR, NXT) do {                        \
    STAGE1((tt) + 2, SB);                                            \
    VMW(4); BAR();                                                   \
    rd_ph1(&As[(CB) * 8192], a47##CUR);                              \
    LKWN(4); SB0();                                                  \
    mf_ph0(a03##CUR, b##CUR);                                        \
    rd_ph0(&As[(NB) * 8192], &Bs[(NB) * 8192], a03##NXT, b##NXT);    \
    LKWN(8); SB0(); BAR();                                           \
    mf_ph1(a47##CUR, b##CUR);                                        \
  } while (0)

  // Prologue: stage tiles 0,1; confirm 0; read its ph0 frags into set A.
  STAGE1(0, 0);
  STAGE1(1, 1);
  VMW(4); BAR();
  rd_ph0(&As[0], &Bs[0], a03A, bA);

#pragma unroll 1
  for (int t = 0; t < 30; t += 6) {     // bodies 0..29, stages 2..31
    G1BODY(t + 0, 0, 1, 2, A, B);
    G1BODY(t + 1, 1, 2, 0, B, A);
    G1BODY(t + 2, 2, 0, 1, A, B);
    G1BODY(t + 3, 0, 1, 2, B, A);
    G1BODY(t + 4, 1, 2, 0, A, B);
    G1BODY(t + 5, 2, 0, 1, B, A);
  }
  // body 30 (CB=0, CUR=A): last loads (tile 31) drained here.
  VMW(0); BAR();
  rd_ph1(&As[0], a47A);
  LKWN(4); SB0();
  mf_ph0(a03A, bA);
  rd_ph0(&As[1 * 8192], &Bs[1 * 8192], a03B, bB);
  LKWN(8); SB0(); BAR();
  mf_ph1(a47A, bA);
  // body 31 (CB=1, CUR=B)
  rd_ph1(&As[1 * 8192], a47B);
  LKWN(4); SB0();
  mf_ph0(a03B, bB);
  LKWN(0); SB0();
  mf_ph1(a47B, bB);

  // Epilogue: gelu( acc + b1 + scale*p1*even ), bf16 store to hact.
  const float sc = scale_p[0];
  const int bidx = m0 >> 11;
  const int i1 = (n0 + wn2 * 64) >> 10;      // wave-uniform lora index
  const float* exrow = x + ((size_t)(bidx * 2048 + 1 + 2 * i1)) * DDIM;

  float exv[4], b1v[4]; int nn[4];
#pragma unroll
  for (int j = 0; j < 4; ++j) {
    nn[j]  = n0 + wn2 * 64 + j * 16 + l16;
    exv[j] = exrow[nn[j] & 1023];
    b1v[j] = b1[nn[j]];
  }
#pragma unroll
  for (int i = 0; i < 8; ++i) {
#pragma unroll
    for (int r = 0; r < 4; ++r) {
      const int m = m0 + wm2 * 128 + i * 16 + quad * 4 + r;
      const float pv = p1[(size_t)m * 4 + i1] * sc;
#pragma unroll
      for (int j = 0; j < 4; ++j) {
        float v = acc[i][j][r] + b1v[j] + pv * exv[j];
        hact[(size_t)m * HDIM + nn[j]] = f2bf(fast_gelu(v));
      }
    }
  }
#undef G1BODY
#undef STAGE1
}

// ---------------------------------------------------------------------------
// GEMM2 v5: 256m x 128n, BK=64, ring-3 (144 KB), frag double-buffer with
// counted lgkmcnt. Phases = k-slices (kk=0 -> set K0, kk=32 -> set K1).
// Same hazard proof as gemm1. p2 fused on matrix pipe (static-index
// wave-uniform selects — rule #20).
// ---------------------------------------------------------------------------
__global__ __launch_bounds__(512, 2) void gemm2_kernel(
    const unsigned short* __restrict__ hact, const unsigned short* __restrict__ w2b,
    const float* __restrict__ x, const float* __restrict__ b2,
    const float* __restrict__ scale_p, float* __restrict__ out) {
  __shared__ __align__(16) unsigned short As[3 * 256 * 64];   // 96 KB
  __shared__ __align__(16) unsigned short Bs[3 * 128 * 64];   // 48 KB
  __shared__ __align__(16) unsigned short od_lds[1024];       // 2 KB
  __shared__ __align__(16) float p2s[256 * 4];                // 4 KB

  const int id = blockIdx.x;                 // 256 blocks = 1/CU
  const int xcd = id & 7, w = id >> 3;       // 32 blocks per XCD
  const int m0 = (xcd * 4 + (w & 3)) * 256;  // 32 m-tiles
  const int n0 = (w >> 2) * 128;             // 8 n-tiles
  const int tid = threadIdx.x;
  const int wave = tid >> 6, lane = tid & 63, quad = lane >> 4, l16 = lane & 15;
  const int wmq = (wave >> 1) * 64;          // wave m-offset (4 quadrants)
  const int wnq = (wave & 1) * 64;           // wave n-offset (2 halves)
  const bool hi = (wave & 1);                // pacc covers acc rows 2*hi..2*hi+1
  const int bidx = m0 >> 11;
  const int i2 = n0 >> 8;                    // block-uniform lora index

  // preload od row (odd token 4+i2) as bf16: 1024 floats, 4 per thread
  if (tid < 256) {
    const float4* src = (const float4*)(x + ((size_t)(bidx * 2048 + 10 + 2 * i2)) * DDIM);
    float4 v = src[tid];
    ushort4 o; o.x = f2bf(v.x); o.y = f2bf(v.y); o.z = f2bf(v.z); o.w = f2bf(v.w);
    ((ushort4*)od_lds)[tid] = o;
  }
  LKWN(0);   // own od ds_write drained; prologue BAR publishes it

  f32x4 acc[4][4];
  const f32x4 z = {0.f, 0.f, 0.f, 0.f};
#pragma unroll
  for (int i = 0; i < 4; ++i)
#pragma unroll
    for (int j = 0; j < 4; ++j) acc[i][j] = z;
  f32x4 pacc[2] = {z, z};
  const bf16x8 zer8 = __builtin_bit_cast(bf16x8, z);

  const unsigned short *gA[4], *gB[2];
#pragma unroll
  for (int s = 0; s < 4; ++s) {
    int idx = (wave * 4 + s) * 64 + lane;
    int r = idx >> 3, sl = idx & 7, c = (sl - r) & 7;
    gA[s] = hact + (size_t)(m0 + r) * HDIM + c * 8;
  }
#pragma unroll
  for (int s = 0; s < 2; ++s) {
    int idx = (wave * 2 + s) * 64 + lane;
    int r = idx >> 3, sl = idx & 7, c = (sl - r) & 7;
    gB[s] = w2b + (size_t)(n0 + r) * HDIM + c * 8;
  }

#define STAGE2(tt, sb) do {                                   \
    const int _k = (tt) * 64;                                 \
    unsigned short* _a = &As[(sb) * 16384];                   \
    unsigned short* _b = &Bs[(sb) * 8192];                    \
    gld_lds16(gA[0] + _k, _a + (wave * 4 + 0) * 512);         \
    gld_lds16(gA[1] + _k, _a + (wave * 4 + 1) * 512);         \
    gld_lds16(gA[2] + _k, _a + (wave * 4 + 2) * 512);         \
    gld_lds16(gA[3] + _k, _a + (wave * 4 + 3) * 512);         \
    gld_lds16(gB[0] + _k, _b + (wave * 2 + 0) * 512);         \
    gld_lds16(gB[1] + _k, _b + (wave * 2 + 1) * 512);         \
  } while (0)

  // two frag sets: K0 = kk=0 phase, K1 = kk=32 phase
  bf16x8 aK0[4], bK0[4], odv0;
  bf16x8 aK1[4], bK1[4], odv1;

  auto rd_ph = [&](const unsigned short* Ab, const unsigned short* Bb,
                   int kk, int odk, bf16x8 (&aa)[4], bf16x8 (&bb)[4], bf16x8& ov) {
    ov = *(const bf16x8*)(od_lds + odk + kk + quad * 8);  // quad-broadcast
    const int cb = (kk >> 3) + quad;
#pragma unroll
    for (int j = 0; j < 4; ++j) {
      const int rb = wnq + j * 16 + l16;
      bb[j] = *(const bf16x8*)(Bb + rb * 64 + ((cb + rb) & 7) * 8);
    }
#pragma unroll
    for (int i = 0; i < 4; ++i) {
      const int ra = wmq + i * 16 + l16;
      aa[i] = *(const bf16x8*)(Ab + ra * 64 + ((cb + ra) & 7) * 8);
    }
  };
  auto mf_ph = [&](bf16x8 (&aa)[4], bf16x8 (&bb)[4], bf16x8& ov) {
    // fused p2 dot (od in column 0 only); static indices + uniform select
    bf16x8 bod = (l16 == 0) ? ov : zer8;
    bf16x8 pa0 = hi ? aa[2] : aa[0];
    bf16x8 pa1 = hi ? aa[3] : aa[1];
    pacc[0] = __builtin_amdgcn_mfma_f32_16x16x32_bf16(pa0, bod, pacc[0], 0, 0, 0);
    pacc[1] = __builtin_amdgcn_mfma_f32_16x16x32_bf16(pa1, bod, pacc[1], 0, 0, 0);
    __builtin_amdgcn_s_setprio(1);
#pragma unroll
    for (int i = 0; i < 4; ++i)
#pragma unroll
      for (int j = 0; j < 4; ++j)
        acc[i][j] = __builtin_amdgcn_mfma_f32_16x16x32_bf16(aa[i], bb[j], acc[i][j], 0, 0, 0);
    __builtin_amdgcn_s_setprio(0);
  };
  auto flush_p2 = [&](int seg) {
    const int ibase = hi ? 2 : 0;            // address arithmetic only — legal
    if (l16 == 0) {
#pragma unroll
      for (int ip = 0; ip < 2; ++ip)
#pragma unroll
        for (int e = 0; e < 4; ++e)
          p2s[(wmq + (ibase + ip) * 16 + quad * 4 + e) * 4 + seg] = pacc[ip][e];
    }
    pacc[0] = z; pacc[1] = z;
  };

#define G2BODY(tt, CB, NB, SB) do {                                         \
    STAGE2((tt) + 2, SB);                                                   \
    VMW(6); BAR();                                                          \
    rd_ph(&As[(CB) * 16384], &Bs[(CB) * 8192], 32, ((tt) * 64) & 1023,      \
          aK1, bK1, odv1);                                                  \
    LKWN(9); SB0();                                                         \
    mf_ph(aK0, bK0, odv0);                                                  \
    rd_ph(&As[(NB) * 16384], &Bs[(NB) * 8192], 0, (((tt) + 1) * 64) & 1023, \
          aK0, bK0, odv0);                                                  \
    LKWN(9); SB0(); BAR();                                                  \
    mf_ph(aK1, bK1, odv1);                                                  \
    if (((tt) & 15) == 15) flush_p2((tt) >> 4);                             \
  } while (0)

  // Prologue: stage 0,1; confirm 0 (and od publish); read tile-0 k0 frags.
  STAGE2(0, 0);
  STAGE2(1, 1);
  VMW(6); BAR();
  rd_ph(&As[0], &Bs[0], 0, 0, aK0, bK0, odv0);

#pragma unroll 1
  for (int t = 0; t < 60; t += 3) {     // bodies 0..59, stages 2..61
    G2BODY(t + 0, 0, 1, 2);
    G2BODY(t + 1, 1, 2, 0);
    G2BODY(t + 2, 2, 0, 1);
  }
  G2BODY(60, 0, 1, 2);                  // stages 62
  G2BODY(61, 1, 2, 0);                  // stages 63 (last)
  // body 62 (CB=2, NB=0): drain last loads.
  VMW(0); BAR();
  rd_ph(&As[2 * 16384], &Bs[2 * 8192], 32, 896, aK1, bK1, odv1);
  LKWN(9); SB0();
  mf_ph(aK0, bK0, odv0);
  rd_ph(&As[0], &Bs[0], 0, 960, aK0, bK0, odv0);
  LKWN(9); SB0(); BAR();
  mf_ph(aK1, bK1, odv1);
  // body 63 (CB=0)
  rd_ph(&As[0], &Bs[0], 32, 960, aK1, bK1, odv1);
  LKWN(9); SB0();
  mf_ph(aK0, bK0, odv0);
  LKWN(0); SB0();
  mf_ph(aK1, bK1, odv1);
  flush_p2(3);
  LKWN(0);                               // own p2s writes drained
  BAR();                                 // p2s visible to all waves

  const float sc = scale_p[0];
  const float* evrow = x + ((size_t)(bidx * 2048 + 9 + 2 * i2)) * DDIM;

  float4 ev[4]; float b2v[4]; int nn[4];
#pragma unroll
  for (int j = 0; j < 4; ++j) {
    nn[j] = n0 + wnq + j * 16 + l16;
    ev[j]  = *(const float4*)(evrow + 4 * (nn[j] & 255));
    b2v[j] = b2[nn[j]];
  }
#pragma unroll
  for (int i = 0; i < 4; ++i) {
#pragma unroll
    for (int r = 0; r < 4; ++r) {
      const int mloc = wmq + i * 16 + quad * 4 + r;
      const int m = m0 + mloc;
      const float4 pv = *(const float4*)(p2s + mloc * 4);  // broadcast across l16
#pragma unroll
      for (int j = 0; j < 4; ++j) {
        float lora = ev[j].x * pv.x + ev[j].y * pv.y + ev[j].z * pv.z + ev[j].w * pv.w;
        out[(size_t)m * DDIM + nn[j]] = acc[i][j][r] + b2v[j] + sc * lora;
      }
    }
  }
#undef G2BODY
#undef STAGE2
}

extern "C" void kernel_launch(void* const* d_in, const int* in_sizes, int n_in,
                              void* d_out, int out_size, void* d_ws, size_t ws_size,
                              hipStream_t stream) {
  const float* x     = (const float*)d_in[0];
  const float* W1    = (const float*)d_in[1];
  const float* b1    = (const float*)d_in[2];
  const float* W2    = (const float*)d_in[3];
  const float* b2    = (const float*)d_in[4];
  const float* scale = (const float*)d_in[5];
  float* out = (float*)d_out;

  char* ws = (char*)d_ws;
  unsigned short* xb   = (unsigned short*)(ws);                // 16 MiB
  unsigned short* w1b  = (unsigned short*)(ws + 16777216);     //  8 MiB
  unsigned short* w2b  = (unsigned short*)(ws + 25165824);     //  8 MiB
  unsigned short* hact = (unsigned short*)(ws + 33554432);     // 64 MiB
  float*          p1   = (float*)(ws + 100663296);             // 128 KiB

  pre_kernel<<<dim3(10240), dim3(256), 0, stream>>>(x, W1, W2, xb, w1b, w2b, p1);
  gemm1_kernel<<<dim3(512), dim3(512), 0, stream>>>(xb, w1b, x, b1, p1, scale, hact);
  gemm2_kernel<<<dim3(256), dim3(512), 0, stream>>>(hact, w2b, x, b2, scale, out);
}